// Round 10
// baseline (298.179 us; speedup 1.0000x reference)
//
#include <hip/hip_runtime.h>
#include <stdint.h>

typedef uint16_t u16;
typedef uint32_t u32;
typedef __bf16 bf16_t;
typedef __bf16 bf16x8 __attribute__((ext_vector_type(8)));
typedef __bf16 bf16x4 __attribute__((ext_vector_type(4)));
typedef float  f32x4  __attribute__((ext_vector_type(4)));

#define MFMA16(a,b,c) __builtin_amdgcn_mfma_f32_16x16x32_bf16(a,b,c,0,0,0)

static __device__ __forceinline__ u16 f2bf(float f){
  union { bf16_t b; u16 u; } cv; cv.b = (bf16_t)f; return cv.u;
}
static __device__ __forceinline__ u32 pack2(float a, float b){
  return (u32)f2bf(a) | ((u32)f2bf(b) << 16);
}

// ---------------- K1: fused Q/K/V projection + (y==3) bias table + gate zero. -------------
// C[8192,256] = X @ W^T + b (f32 in, bf16 MFMA, bf16 out), reg-prefetch double-buffered.
// Wsh/Cs union keeps LDS at 35.8KB -> 3 blocks/CU resident in one dispatch round.
__global__ __attribute__((amdgpu_waves_per_eu(3, 3))) __launch_bounds__(256) void k_proj3b(
    const float* __restrict__ X,
    const float* __restrict__ Wq, const float* __restrict__ Bq,
    const float* __restrict__ Wk, const float* __restrict__ Bk,
    const float* __restrict__ Wv, const float* __restrict__ Bvv,
    u16* __restrict__ Qo, u16* __restrict__ Ko, u16* __restrict__ Vo,
    float qscale,
    const float* __restrict__ dist_bias, const float* __restrict__ dir_bias,
    float* __restrict__ ebtab, int* __restrict__ gate)
{
  if (blockIdx.y == 3){
    // bias table blocks (16 of them) + gate zero; other x-blocks exit.
    if (blockIdx.x == 0 && threadIdx.x == 0) *gate = 0;
    int tid = blockIdx.x*256 + threadIdx.x;
    if (blockIdx.x >= 16 || tid >= 63*63) return;
    int dhi = tid / 63, dwi = tid % 63;
    int dh = dhi - 31, dw = dwi - 31;
    int dist = (int)sqrtf((float)(dh*dh + dw*dw));
    if (dist > 59) dist = 59;
    int dir;
    if (dh==0 && dw==0)      dir = 0;
    else if (dh==0)          dir = (dw>0) ? 8  : 0;
    else if (dw==0)          dir = (dh>0) ? 12 : 4;
    else if (dh==dw)         dir = (dh>0) ? 10 : 2;
    else if (dh==-dw)        dir = (dh>0) ? 14 : 6;
    else {
      float ang = atan2f((float)dh, (float)dw) + 3.14159265358979323846f;
      int k = (int)floorf(ang * 2.5464790894703254f);
      dir = k & 15;
    }
    for (int h=0; h<8; h++){
      ebtab[dhi*512 + h*64 + dwi] = expf(dist_bias[dist*8+h] + dir_bias[dir*8+h]);
    }
    return;
  }

  const float* W; const float* Bv; u16* Out; float scale; int vt_mode;
  if (blockIdx.y == 0)      { W = Wq; Bv = Bq;  Out = Qo; scale = qscale; vt_mode = 0; }
  else if (blockIdx.y == 1) { W = Wk; Bv = Bk;  Out = Ko; scale = 1.0f;   vt_mode = 0; }
  else                      { W = Wv; Bv = Bvv; Out = Vo; scale = 1.0f;   vt_mode = 1; }

  __shared__ bf16_t Xs[32*40];
  __shared__ __align__(16) char UU[33280];   // union: Wsh bf16[256*40]=20480B | Cs f32[32*260]=33280B
  bf16_t* Wsh = (bf16_t*)UU;
  float*  Cs  = (float*)UU;
  const int t = threadIdx.x;
  const int wv = t>>6, ln = t&15, qd = (t&63)>>4;
  const int wm = wv & 1, wn = wv >> 1;
  const int m0 = blockIdx.x * 32;

  f32x4 z4 = {0.0f,0.0f,0.0f,0.0f};
  f32x4 acc[8];
  #pragma unroll
  for (int i=0;i<8;i++) acc[i] = z4;

  f32x4 XR; f32x4 WR[8];
  XR = *(const f32x4*)(X + (size_t)(m0 + (t>>3))*256 + (t&7)*4);
  #pragma unroll
  for (int j=0;j<8;j++)
    WR[j] = *(const f32x4*)(W + (size_t)((t>>3)+32*j)*256 + (t&7)*4);

  for (int kt=0; kt<8; kt++){
    __syncthreads();
    { int m = t>>3, k0 = (t&7)*4;
      uint2 pk; pk.x = pack2(XR[0], XR[1]); pk.y = pack2(XR[2], XR[3]);
      *(uint2*)&Xs[m*40 + k0] = pk;
    }
    #pragma unroll
    for (int j=0;j<8;j++){
      int n = (t>>3) + 32*j, k0 = (t&7)*4;
      uint2 pk; pk.x = pack2(WR[j][0], WR[j][1]); pk.y = pack2(WR[j][2], WR[j][3]);
      *(uint2*)&Wsh[n*40 + k0] = pk;
    }
    __syncthreads();
    if (kt < 7){
      XR = *(const f32x4*)(X + (size_t)(m0 + (t>>3))*256 + (kt+1)*32 + (t&7)*4);
      #pragma unroll
      for (int j=0;j<8;j++)
        WR[j] = *(const f32x4*)(W + (size_t)((t>>3)+32*j)*256 + (kt+1)*32 + (t&7)*4);
    }
    bf16x8 a = *(const bf16x8*)&Xs[(wm*16+ln)*40 + qd*8];
    #pragma unroll
    for (int ni=0;ni<8;ni++){
      bf16x8 bb = *(const bf16x8*)&Wsh[(wn*128 + ni*16 + ln)*40 + qd*8];
      acc[ni] = MFMA16(a, bb, acc[ni]);
    }
  }
  __syncthreads();   // Wsh dead after this point; Cs takes over the union
  #pragma unroll
  for (int ni=0;ni<8;ni++){
    const int col = wn*128 + ni*16 + ln;
    const float bias = Bv[col];
    #pragma unroll
    for (int r=0;r<4;r++){
      Cs[(wm*16 + qd*4 + r)*260 + col] = (acc[ni][r] + bias) * scale;
    }
  }
  __syncthreads();
  if (!vt_mode){
    int row = t>>3, c0 = (t&7)*32;
    u16* op = Out + (size_t)(m0+row)*256 + c0;
    #pragma unroll
    for (int i=0;i<4;i++){
      f32x4 v0 = *(const f32x4*)&Cs[row*260 + c0 + i*8];
      f32x4 v1 = *(const f32x4*)&Cs[row*260 + c0 + i*8 + 4];
      union { u16 h[8]; uint4 v; } pk;
      #pragma unroll
      for (int e=0;e<4;e++){ pk.h[e] = f2bf(v0[e]); pk.h[4+e] = f2bf(v1[e]); }
      *(uint4*)(op + i*8) = pk.v;
    }
  } else {
    const int n = t;
    const int b = m0 >> 10, s0 = m0 & 1023;
    u16* op = Out + (size_t)(b*256 + n)*1024 + s0;
    #pragma unroll
    for (int i=0;i<4;i++){
      union { u16 h[8]; uint4 v; } pk;
      #pragma unroll
      for (int e=0;e<8;e++) pk.h[e] = f2bf(Cs[(i*8+e)*260 + n]);
      *(uint4*)(op + i*8) = pk.v;
    }
  }
}

// ---------------- K2a: attention ctx pass: one head per block, kt-range per wave. ---------
// Grid (64 qt, 8 b, 8 h) = 4096 blocks; wave wv owns kt in [wv*8, wv*8+8). Cross-wave
// combine of se/sb/oacc in LDS (2 barriers). (4,8): budget from min=4 (128 regs, needs
// 52 -> no spill) while max=8 lifts the r9 (4,4) occupancy cap (40% measured).
__global__ __attribute__((amdgpu_waves_per_eu(4, 8))) __launch_bounds__(256) void k_attn_ctx(
    const u16* __restrict__ Qg, const u16* __restrict__ Kg,
    const u16* __restrict__ Vtg, const float* __restrict__ ebtab,
    u16* __restrict__ ctx, float* __restrict__ sden)
{
  __shared__ bf16_t Ps[4][16*40];          // 5120 B, wave-private transpose buffer
  __shared__ float  red[2][4][16];         // 512 B: se/sb per wave per row
  __shared__ float  invb[16];              // 64 B
  __shared__ float  opl[4][16][33];        // 8448 B (pad 33: no 4-way bank alias)

  const int t  = threadIdx.x;
  const int wv = t >> 6;
  const int ln = t & 15;
  const int qd = (t & 63) >> 4;
  const int lane = t & 63;
  const int b  = blockIdx.y;
  const int qt = blockIdx.x;
  const int h  = blockIdx.z;
  const int kt0 = wv*8;
  const int qh_img = qt >> 1;
  const int qw0 = (qt & 1) * 16;

  const u16* Qb  = Qg  + (size_t)(b*1024 + qt*16) * 256;
  const u16* Kb  = Kg  + (size_t)b * 1024 * 256;
  const u16* Vtb = Vtg + (size_t)b * 256 * 1024;

  f32x4 z4 = {0.0f,0.0f,0.0f,0.0f};

  bf16x8 aq = *(const bf16x8*)(Qb + ln*256 + h*32 + qd*8);

  float se[4] = {0,0,0,0}, sb[4] = {0,0,0,0};
  f32x4 oacc[2]; oacc[0]=z4; oacc[1]=z4;

  for (int kti=0; kti<8; kti++){
    const int kt = kt0 + kti;
    float cE = ebtab[(size_t)(kt - qh_img + 31)*512 + h*64 + lane];

    #pragma unroll
    for (int kh=0;kh<2;kh++){
      bf16x8 bk = *(const bf16x8*)(Kb + (size_t)(kt*32 + kh*16 + ln)*256 + h*32 + qd*8);
      f32x4 sc = MFMA16(aq, bk, z4);
      #pragma unroll
      for (int r=0;r<4;r++){
        float e  = exp2f(sc[r]);                 // Q pre-scaled by log2e/sqrt(dk)
        int idx = kh*16 + ln - (qw0 + qd*4 + r) + 31;   // dw+31 in [0,62]
        float ebv = __shfl(cE, idx);
        float eb = e * ebv;
        se[r] += e;
        sb[r] += eb;
        Ps[wv][(qd*4+r)*40 + kh*16 + ln] = (bf16_t)eb;   // unnormalized
      }
    }
    // per-wave in-order LDS + alias-visible dependence orders Ps write->read
    bf16x8 ap = *(const bf16x8*)&Ps[wv][ln*40 + qd*8];
    #pragma unroll
    for (int nh=0;nh<2;nh++){
      bf16x8 bv = *(const bf16x8*)(Vtb + (size_t)(h*32 + nh*16 + ln)*1024 + kt*32 + qd*8);
      oacc[nh] = MFMA16(ap, bv, oacc[nh]);
    }
  }

  // reduce partial denominator sums across the 16 column-lanes (same qd group)
  #pragma unroll
  for (int r=0;r<4;r++){
    #pragma unroll
    for (int m=1;m<16;m<<=1){
      se[r] += __shfl_xor(se[r], m, 16);
      sb[r] += __shfl_xor(sb[r], m, 16);
    }
  }
  if (ln == 0){
    #pragma unroll
    for (int r=0;r<4;r++){
      red[0][wv][qd*4+r] = se[r];
      red[1][wv][qd*4+r] = sb[r];
    }
  }
  // stage this wave's PV partial
  #pragma unroll
  for (int nh=0;nh<2;nh++)
    #pragma unroll
    for (int r=0;r<4;r++)
      opl[wv][qd*4+r][nh*16+ln] = oacc[nh][r];
  __syncthreads();

  if (t < 16){
    float s = red[0][0][t] + red[0][1][t] + red[0][2][t] + red[0][3][t];
    float bsum = red[1][0][t] + red[1][1][t] + red[1][2][t] + red[1][3][t];
    sden[(size_t)(b*8 + h)*1024 + qt*16 + t] = 1.0f / s;
    invb[t] = 1.0f / bsum;
  }
  __syncthreads();

  { // 256 threads: 16 rows x 32 cols, 2 cols/thread -> ctx bf16
    const int row = t >> 4, c = (t & 15)*2;
    float o0 = opl[0][row][c]   + opl[1][row][c]   + opl[2][row][c]   + opl[3][row][c];
    float o1 = opl[0][row][c+1] + opl[1][row][c+1] + opl[2][row][c+1] + opl[3][row][c+1];
    float iv = invb[row];
    *(u32*)(ctx + (size_t)(b*1024 + qt*16 + row)*256 + h*32 + c) = pack2(o0*iv, o1*iv);
  }
}

// ---------------- K2b+K3 packed: z<4 = attn_w blocks; z==4 = out-proj+LN blocks. ----------
// aw (reads Q,K) and outln (writes y, which ALIASES Q,K storage) are data-independent
// except for that alias -> device-scope atomic gate: aw blocks count in after their
// loads complete (syncthreads + threadfence); outln blocks compute Ys fully, spin on
// the gate (acquire), then do the final y write. Co-scheduling fills both kernels'
// latency stalls (both were <35% busy). Gate zeroed each graph exec by k_proj3b.
__global__ __attribute__((amdgpu_waves_per_eu(2, 4))) __launch_bounds__(256) void k_awln(
    const u16* __restrict__ Qg, const u16* __restrict__ Kg,
    const float* __restrict__ sden, float* __restrict__ AW,
    const u16* __restrict__ CX, const float* __restrict__ Wo,
    const float* __restrict__ bo, const float* __restrict__ xs,
    const float* __restrict__ lgm, const float* __restrict__ lbt,
    float* __restrict__ Out, int* __restrict__ gate)
{
  __shared__ bf16_t Cts[16*40];
  __shared__ __align__(16) char UU[20480];   // union: Wsh bf16[256*40] | Ys f32[16*260]
  bf16_t* Wsh = (bf16_t*)UU;
  float*  Ys  = (float*)UU;
  __shared__ float parts[4][16][2];

  const int t  = threadIdx.x;
  const int wv = t >> 6;
  const int ln = t & 15;
  const int qd = (t & 63) >> 4;
  f32x4 z4 = {0.0f,0.0f,0.0f,0.0f};

  if (blockIdx.z < 4){
    // ---------------- attn_w path ----------------
    const int b  = blockIdx.y;
    const int qt = blockIdx.x;
    const int kt0 = blockIdx.z*8 + wv*2;

    const u16* Qb = Qg + (size_t)(b*1024 + qt*16) * 256;
    const u16* Kb = Kg + (size_t)b * 1024 * 256;

    bf16x8 aqh[8];
    #pragma unroll
    for (int h=0;h<8;h++)
      aqh[h] = *(const bf16x8*)(Qb + ln*256 + h*32 + qd*8);

    float aw0[2][2][4];
    #pragma unroll
    for (int k2=0;k2<2;k2++)
      #pragma unroll
      for (int kh=0;kh<2;kh++)
        #pragma unroll
        for (int r=0;r<4;r++) aw0[k2][kh][r] = 0.0f;

    #pragma unroll
    for (int h=0;h<8;h++){
      float iv[4];
      #pragma unroll
      for (int r=0;r<4;r++)
        iv[r] = sden[(size_t)(b*8 + h)*1024 + qt*16 + qd*4 + r];
      #pragma unroll
      for (int k2=0;k2<2;k2++){
        #pragma unroll
        for (int kh=0;kh<2;kh++){
          bf16x8 bk = *(const bf16x8*)(Kb + (size_t)((kt0+k2)*32 + kh*16 + ln)*256 + h*32 + qd*8);
          f32x4 sc = MFMA16(aqh[h], bk, z4);
          #pragma unroll
          for (int r=0;r<4;r++)
            aw0[k2][kh][r] += exp2f(sc[r]) * iv[r];
        }
      }
    }
    #pragma unroll
    for (int k2=0;k2<2;k2++)
      #pragma unroll
      for (int kh=0;kh<2;kh++)
        #pragma unroll
        for (int r=0;r<4;r++)
          AW[(size_t)(b*1024 + qt*16 + qd*4 + r)*1024 + (kt0+k2)*32 + kh*16 + ln]
              = aw0[k2][kh][r] * 0.125f;

    __syncthreads();            // all waves' Q/K loads completed (values consumed)
    if (t == 0){
      __threadfence();
      atomicAdd(gate, 1);
    }
    return;
  }

  // ---------------- out-proj + LN path ----------------
  const int m0 = (blockIdx.y*64 + blockIdx.x) * 16;

  f32x4 acc[4];
  #pragma unroll
  for (int i=0;i<4;i++) acc[i] = z4;

  u32 CR; f32x4 WR[8];
  CR = *(const u32*)(CX + (size_t)(m0 + (t>>4))*256 + (t&15)*2);
  #pragma unroll
  for (int j=0;j<8;j++)
    WR[j] = *(const f32x4*)(Wo + (size_t)((t>>3)+32*j)*256 + (t&7)*4);

  for (int kt=0; kt<8; kt++){
    __syncthreads();
    *(u32*)&Cts[(t>>4)*40 + (t&15)*2] = CR;
    #pragma unroll
    for (int j=0;j<8;j++){
      int n = (t>>3) + 32*j, k0 = (t&7)*4;
      uint2 pk; pk.x = pack2(WR[j][0], WR[j][1]); pk.y = pack2(WR[j][2], WR[j][3]);
      *(uint2*)&Wsh[n*40 + k0] = pk;
    }
    __syncthreads();
    if (kt < 7){
      CR = *(const u32*)(CX + (size_t)(m0 + (t>>4))*256 + (kt+1)*32 + (t&15)*2);
      #pragma unroll
      for (int j=0;j<8;j++)
        WR[j] = *(const f32x4*)(Wo + (size_t)((t>>3)+32*j)*256 + (kt+1)*32 + (t&7)*4);
    }
    bf16x8 a = *(const bf16x8*)&Cts[ln*40 + qd*8];
    #pragma unroll
    for (int ni=0;ni<4;ni++){
      bf16x8 bb = *(const bf16x8*)&Wsh[(wv*64 + ni*16 + ln)*40 + qd*8];
      acc[ni] = MFMA16(a, bb, acc[ni]);
    }
  }

  float psum[4]={0,0,0,0}, psq[4]={0,0,0,0};
  #pragma unroll
  for (int ni=0;ni<4;ni++){
    const int col = wv*64 + ni*16 + ln;
    const float bias = bo[col];
    #pragma unroll
    for (int r=0;r<4;r++){
      const int row = qd*4 + r;
      float y = acc[ni][r] + bias + xs[(size_t)(m0+row)*256 + col];
      acc[ni][r] = y;
      psum[r] += y; psq[r] += y*y;
    }
  }
  #pragma unroll
  for (int r=0;r<4;r++){
    float a1 = psum[r], a2 = psq[r];
    #pragma unroll
    for (int m=1;m<16;m<<=1){ a1 += __shfl_xor(a1,m,16); a2 += __shfl_xor(a2,m,16); }
    if (ln == 0){
      parts[wv][qd*4 + r][0] = a1;
      parts[wv][qd*4 + r][1] = a2;
    }
  }
  __syncthreads();   // also: all Wsh reads done -> Ys may take over the union
  #pragma unroll
  for (int r=0;r<4;r++){
    const int row = qd*4 + r;
    float s1 = parts[0][row][0] + parts[1][row][0] + parts[2][row][0] + parts[3][row][0];
    float s2 = parts[0][row][1] + parts[1][row][1] + parts[2][row][1] + parts[3][row][1];
    float mu  = s1 * 0.00390625f;
    float var = s2 * 0.00390625f - mu*mu;
    float rs = rsqrtf(var + 1e-5f);
    #pragma unroll
    for (int ni=0;ni<4;ni++){
      const int col = wv*64 + ni*16 + ln;
      Ys[row*260 + col] = (acc[ni][r] - mu)*rs*lgm[col] + lbt[col];
    }
  }
  __syncthreads();

  // gate: wait until all 2048 aw blocks have finished reading Q/K (aliased with Out)
  if (t == 0){
    while (__hip_atomic_load(gate, __ATOMIC_ACQUIRE, __HIP_MEMORY_SCOPE_AGENT) < 2048)
      __builtin_amdgcn_s_sleep(2);
  }
  __syncthreads();

  { int row = t>>4, c0 = (t&15)*16;
    float* op = Out + (size_t)(m0+row)*256 + c0;
    #pragma unroll
    for (int i=0;i<4;i++)
      *(f32x4*)(op + 4*i) = *(const f32x4*)&Ys[row*260 + c0 + 4*i];
  }
}

// -----------------------------------------------------------------------------------------
extern "C" void kernel_launch(void* const* d_in, const int* in_sizes, int n_in,
                              void* d_out, int out_size, void* d_ws, size_t ws_size,
                              hipStream_t stream)
{
  const float* x   = (const float*)d_in[0];
  const float* wq  = (const float*)d_in[1];
  const float* bq  = (const float*)d_in[2];
  const float* wk  = (const float*)d_in[3];
  const float* bk  = (const float*)d_in[4];
  const float* wv_ = (const float*)d_in[5];
  const float* bv  = (const float*)d_in[6];
  const float* wo  = (const float*)d_in[7];
  const float* bo  = (const float*)d_in[8];
  const float* lng = (const float*)d_in[9];
  const float* lnb = (const float*)d_in[10];
  const float* dib = (const float*)d_in[11];
  const float* drb = (const float*)d_in[12];

  // ws: ebtab 128K | CX bf16 4MB | Vt bf16 4MB | sden f32 256K | gate 4B = 8.78 MB.
  // d_out f32: y [0, 8MB) ; attn_w [8MB, 41.5MB).
  //   Q bf16 at y [0,4M), K bf16 at y [4M,8M) -> protected from k_awln's y writes by
  //   the atomic gate (aw blocks count in after reading; outln blocks wait).
  char*  ws    = (char*)d_ws;
  float* ebtab = (float*)ws;
  u16*   CX    = (u16*)(ws + 131072);
  u16*   Vt    = (u16*)(ws + 131072 + 4194304);
  float* sden  = (float*)(ws + 131072 + 8388608);
  int*   gate  = (int*)(ws + 131072 + 8388608 + 262144);
  float* y     = (float*)d_out;
  float* aw    = y + 2097152;
  u16*   Q     = (u16*)y;
  u16*   K     = (u16*)((char*)y + 4194304);

  const float qscale = 0.25503486f;   // log2(e)/sqrt(32) folded into Q

  k_proj3b<<<dim3(256, 4), 256, 0, stream>>>(x, wq, bq, wk, bk, wv_, bv, Q, K, Vt,
                                             qscale, dib, drb, ebtab, gate);
  k_attn_ctx<<<dim3(64, 8, 8), 256, 0, stream>>>(Q, K, Vt, ebtab, CX, sden);
  k_awln<<<dim3(64, 8, 5), 256, 0, stream>>>(Q, K, sden, aw, CX, wo, bo, x,
                                             lng, lnb, y, gate);
}

// Round 11
// 245.009 us; speedup vs baseline: 1.2170x; 1.2170x over previous
//
#include <hip/hip_runtime.h>
#include <stdint.h>

typedef uint16_t u16;
typedef uint32_t u32;
typedef __bf16 bf16_t;
typedef __bf16 bf16x8 __attribute__((ext_vector_type(8)));
typedef float  f32x4  __attribute__((ext_vector_type(4)));

#define MFMA16(a,b,c) __builtin_amdgcn_mfma_f32_16x16x32_bf16(a,b,c,0,0,0)

static __device__ __forceinline__ u16 f2bf(float f){
  union { bf16_t b; u16 u; } cv; cv.b = (bf16_t)f; return cv.u;
}
static __device__ __forceinline__ u32 pack2(float a, float b){
  return (u32)f2bf(a) | ((u32)f2bf(b) << 16);
}

// ---------------- K0: convert X + 4 W matrices to bf16; build exp(bias) table. ------------
// bx<1024: X (2M f32). bx 1024..1039: ebtab. bx 1040..1043: one W matrix each.
__global__ __launch_bounds__(256) void k_convert(
    const float* __restrict__ X, u16* __restrict__ Xb,
    const float* __restrict__ Wq, const float* __restrict__ Wk,
    const float* __restrict__ Wv, const float* __restrict__ Wo,
    u16* __restrict__ Wqb, u16* __restrict__ Wkb,
    u16* __restrict__ Wvb, u16* __restrict__ Wob,
    const float* __restrict__ dist_bias, const float* __restrict__ dir_bias,
    float* __restrict__ ebtab)
{
  const int bx = blockIdx.x, t = threadIdx.x;
  if (bx < 1024){
    const size_t i0 = (size_t)bx*2048 + t*8;
    f32x4 v0 = *(const f32x4*)(X + i0);
    f32x4 v1 = *(const f32x4*)(X + i0 + 4);
    union { u16 h[8]; uint4 v; } pk;
    #pragma unroll
    for (int e=0;e<4;e++){ pk.h[e] = f2bf(v0[e]); pk.h[4+e] = f2bf(v1[e]); }
    *(uint4*)(Xb + i0) = pk.v;
  } else if (bx < 1040){
    int tid = (bx-1024)*256 + t;
    if (tid >= 63*63) return;
    int dhi = tid / 63, dwi = tid % 63;
    int dh = dhi - 31, dw = dwi - 31;
    int dist = (int)sqrtf((float)(dh*dh + dw*dw));
    if (dist > 59) dist = 59;
    int dir;
    if (dh==0 && dw==0)      dir = 0;
    else if (dh==0)          dir = (dw>0) ? 8  : 0;
    else if (dw==0)          dir = (dh>0) ? 12 : 4;
    else if (dh==dw)         dir = (dh>0) ? 10 : 2;
    else if (dh==-dw)        dir = (dh>0) ? 14 : 6;
    else {
      float ang = atan2f((float)dh, (float)dw) + 3.14159265358979323846f;
      int k = (int)floorf(ang * 2.5464790894703254f);
      dir = k & 15;
    }
    for (int h=0; h<8; h++){
      ebtab[dhi*512 + h*64 + dwi] = expf(dist_bias[dist*8+h] + dir_bias[dir*8+h]);
    }
  } else {
    const int wi = bx - 1040;
    const float* src = (wi==0)?Wq:(wi==1)?Wk:(wi==2)?Wv:Wo;
    u16* dst = (wi==0)?Wqb:(wi==1)?Wkb:(wi==2)?Wvb:Wob;
    #pragma unroll
    for (int c=0;c<32;c++){
      const size_t i0 = (size_t)c*2048 + t*8;
      f32x4 v0 = *(const f32x4*)(src + i0);
      f32x4 v1 = *(const f32x4*)(src + i0 + 4);
      union { u16 h[8]; uint4 v; } pk;
      #pragma unroll
      for (int e=0;e<4;e++){ pk.h[e] = f2bf(v0[e]); pk.h[4+e] = f2bf(v1[e]); }
      *(uint4*)(dst + i0) = pk.v;
    }
  }
}

// ---------------- K1: Q/K/V projection, ZERO LDS / ZERO barriers. -------------------------
// All operands bf16 in L2 (X-bf16 4MB, W-bf16 128KB) -> MFMA fragments loaded directly
// global->VGPR (r4 lesson applied to proj: staging L2-resident data was pure overhead).
// 16-row tiles: grid (512,3) = 1536 blocks = 6/CU, 24 waves/CU. Wave owns 16x64 out.
__global__ __attribute__((amdgpu_waves_per_eu(4, 8))) __launch_bounds__(256) void k_proj(
    const u16* __restrict__ Xb,
    const u16* __restrict__ Wqb, const float* __restrict__ Bq,
    const u16* __restrict__ Wkb, const float* __restrict__ Bk,
    const u16* __restrict__ Wvb, const float* __restrict__ Bvv,
    u16* __restrict__ Qo, u16* __restrict__ Ko, u16* __restrict__ Vo,
    float qscale)
{
  const u16* Wb; const float* Bi; u16* Out; float scale; int vt_mode;
  if (blockIdx.y == 0)      { Wb = Wqb; Bi = Bq;  Out = Qo; scale = qscale; vt_mode = 0; }
  else if (blockIdx.y == 1) { Wb = Wkb; Bi = Bk;  Out = Ko; scale = 1.0f;   vt_mode = 0; }
  else                      { Wb = Wvb; Bi = Bvv; Out = Vo; scale = 1.0f;   vt_mode = 1; }

  const int t = threadIdx.x;
  const int wv = t>>6, ln = t&15, qd = (t&63)>>4;
  const int m0 = blockIdx.x * 16;
  const int n0w = wv*64;

  f32x4 z4 = {0.0f,0.0f,0.0f,0.0f};
  f32x4 acc[4];
  #pragma unroll
  for (int i=0;i<4;i++) acc[i] = z4;

  #pragma unroll
  for (int kt=0; kt<8; kt++){
    bf16x8 a = *(const bf16x8*)(Xb + (size_t)(m0 + ln)*256 + kt*32 + qd*8);
    #pragma unroll
    for (int ni=0;ni<4;ni++){
      bf16x8 b = *(const bf16x8*)(Wb + (size_t)(n0w + ni*16 + ln)*256 + kt*32 + qd*8);
      acc[ni] = MFMA16(a, b, acc[ni]);
    }
  }

  if (!vt_mode){
    #pragma unroll
    for (int ni=0;ni<4;ni++){
      const int col = n0w + ni*16 + ln;
      const float bias = Bi[col];
      #pragma unroll
      for (int r=0;r<4;r++)
        Out[(size_t)(m0 + qd*4 + r)*256 + col] = f2bf((acc[ni][r] + bias) * scale);
    }
  } else {
    const int b = m0 >> 10, s0 = m0 & 1023;
    #pragma unroll
    for (int ni=0;ni<4;ni++){
      const int n = n0w + ni*16 + ln;
      const float bias = Bi[n];
      union { u16 h[4]; uint2 u; } pk;
      #pragma unroll
      for (int r=0;r<4;r++) pk.h[r] = f2bf(acc[ni][r] + bias);
      *(uint2*)(Vo + (size_t)(b*256 + n)*1024 + s0 + qd*4) = pk.u;
    }
  }
}

// ---------------- K2a: attention ctx pass (r9, proven 69us): one head per block, ----------
// kt-range per wave; cross-wave combine in LDS (2 barriers). (4,4): 52 VGPR, no spill.
__global__ __attribute__((amdgpu_waves_per_eu(4, 4))) __launch_bounds__(256) void k_attn_ctx(
    const u16* __restrict__ Qg, const u16* __restrict__ Kg,
    const u16* __restrict__ Vtg, const float* __restrict__ ebtab,
    u16* __restrict__ ctx, float* __restrict__ sden)
{
  __shared__ bf16_t Ps[4][16*40];          // 5120 B, wave-private transpose buffer
  __shared__ float  red[2][4][16];         // 512 B: se/sb per wave per row
  __shared__ float  invb[16];              // 64 B
  __shared__ float  opl[4][16][33];        // 8448 B (pad 33: no 4-way bank alias)

  const int t  = threadIdx.x;
  const int wv = t >> 6;
  const int ln = t & 15;
  const int qd = (t & 63) >> 4;
  const int lane = t & 63;
  const int b  = blockIdx.y;
  const int qt = blockIdx.x;
  const int h  = blockIdx.z;
  const int kt0 = wv*8;
  const int qh_img = qt >> 1;
  const int qw0 = (qt & 1) * 16;

  const u16* Qb  = Qg  + (size_t)(b*1024 + qt*16) * 256;
  const u16* Kb  = Kg  + (size_t)b * 1024 * 256;
  const u16* Vtb = Vtg + (size_t)b * 256 * 1024;

  f32x4 z4 = {0.0f,0.0f,0.0f,0.0f};

  bf16x8 aq = *(const bf16x8*)(Qb + ln*256 + h*32 + qd*8);

  float se[4] = {0,0,0,0}, sb[4] = {0,0,0,0};
  f32x4 oacc[2]; oacc[0]=z4; oacc[1]=z4;

  for (int kti=0; kti<8; kti++){
    const int kt = kt0 + kti;
    float cE = ebtab[(size_t)(kt - qh_img + 31)*512 + h*64 + lane];

    #pragma unroll
    for (int kh=0;kh<2;kh++){
      bf16x8 bk = *(const bf16x8*)(Kb + (size_t)(kt*32 + kh*16 + ln)*256 + h*32 + qd*8);
      f32x4 sc = MFMA16(aq, bk, z4);
      #pragma unroll
      for (int r=0;r<4;r++){
        float e  = exp2f(sc[r]);                 // Q pre-scaled by log2e/sqrt(dk)
        int idx = kh*16 + ln - (qw0 + qd*4 + r) + 31;   // dw+31 in [0,62]
        float ebv = __shfl(cE, idx);
        float eb = e * ebv;
        se[r] += e;
        sb[r] += eb;
        Ps[wv][(qd*4+r)*40 + kh*16 + ln] = (bf16_t)eb;   // unnormalized
      }
    }
    // per-wave in-order LDS + alias-visible dependence orders Ps write->read
    bf16x8 ap = *(const bf16x8*)&Ps[wv][ln*40 + qd*8];
    #pragma unroll
    for (int nh=0;nh<2;nh++){
      bf16x8 bv = *(const bf16x8*)(Vtb + (size_t)(h*32 + nh*16 + ln)*1024 + kt*32 + qd*8);
      oacc[nh] = MFMA16(ap, bv, oacc[nh]);
    }
  }

  // reduce partial denominator sums across the 16 column-lanes (same qd group)
  #pragma unroll
  for (int r=0;r<4;r++){
    #pragma unroll
    for (int m=1;m<16;m<<=1){
      se[r] += __shfl_xor(se[r], m, 16);
      sb[r] += __shfl_xor(sb[r], m, 16);
    }
  }
  if (ln == 0){
    #pragma unroll
    for (int r=0;r<4;r++){
      red[0][wv][qd*4+r] = se[r];
      red[1][wv][qd*4+r] = sb[r];
    }
  }
  // stage this wave's PV partial
  #pragma unroll
  for (int nh=0;nh<2;nh++)
    #pragma unroll
    for (int r=0;r<4;r++)
      opl[wv][qd*4+r][nh*16+ln] = oacc[nh][r];
  __syncthreads();

  if (t < 16){
    float s = red[0][0][t] + red[0][1][t] + red[0][2][t] + red[0][3][t];
    float bsum = red[1][0][t] + red[1][1][t] + red[1][2][t] + red[1][3][t];
    sden[(size_t)(b*8 + h)*1024 + qt*16 + t] = 1.0f / s;
    invb[t] = 1.0f / bsum;
  }
  __syncthreads();

  { // 256 threads: 16 rows x 32 cols, 2 cols/thread -> ctx bf16
    const int row = t >> 4, c = (t & 15)*2;
    float o0 = opl[0][row][c]   + opl[1][row][c]   + opl[2][row][c]   + opl[3][row][c];
    float o1 = opl[0][row][c+1] + opl[1][row][c+1] + opl[2][row][c+1] + opl[3][row][c+1];
    float iv = invb[row];
    *(u32*)(ctx + (size_t)(b*1024 + qt*16 + row)*256 + h*32 + c) = pack2(o0*iv, o1*iv);
  }
}

// ---------------- K2b: attn_w pass (r9, proven ~45us). kt-parallel, grid (64,8,4). --------
__global__ __attribute__((amdgpu_waves_per_eu(4, 4))) __launch_bounds__(256) void k_attn_aw(
    const u16* __restrict__ Qg, const u16* __restrict__ Kg,
    const float* __restrict__ sden, float* __restrict__ AW)
{
  const int t  = threadIdx.x;
  const int wv = t >> 6;
  const int ln = t & 15;
  const int qd = (t & 63) >> 4;
  const int b  = blockIdx.y;
  const int qt = blockIdx.x;
  const int kt0 = blockIdx.z*8 + wv*2;

  const u16* Qb = Qg + (size_t)(b*1024 + qt*16) * 256;
  const u16* Kb = Kg + (size_t)b * 1024 * 256;

  f32x4 z4 = {0.0f,0.0f,0.0f,0.0f};

  bf16x8 aqh[8];
  #pragma unroll
  for (int h=0;h<8;h++)
    aqh[h] = *(const bf16x8*)(Qb + ln*256 + h*32 + qd*8);

  float aw0[2][2][4];
  #pragma unroll
  for (int k2=0;k2<2;k2++)
    #pragma unroll
    for (int kh=0;kh<2;kh++)
      #pragma unroll
      for (int r=0;r<4;r++) aw0[k2][kh][r] = 0.0f;

  #pragma unroll
  for (int h=0;h<8;h++){
    float iv[4];
    #pragma unroll
    for (int r=0;r<4;r++)
      iv[r] = sden[(size_t)(b*8 + h)*1024 + qt*16 + qd*4 + r];
    #pragma unroll
    for (int k2=0;k2<2;k2++){
      #pragma unroll
      for (int kh=0;kh<2;kh++){
        bf16x8 bk = *(const bf16x8*)(Kb + (size_t)((kt0+k2)*32 + kh*16 + ln)*256 + h*32 + qd*8);
        f32x4 sc = MFMA16(aqh[h], bk, z4);
        #pragma unroll
        for (int r=0;r<4;r++)
          aw0[k2][kh][r] += exp2f(sc[r]) * iv[r];
      }
    }
  }
  #pragma unroll
  for (int k2=0;k2<2;k2++)
    #pragma unroll
    for (int kh=0;kh<2;kh++)
      #pragma unroll
      for (int r=0;r<4;r++)
        AW[(size_t)(b*1024 + qt*16 + qd*4 + r)*1024 + (kt0+k2)*32 + kh*16 + ln]
            = aw0[k2][kh][r] * 0.125f;
}

// ---------------- K3: out = ctx@Wo^T + bo ; y = LN(out + x). ZERO-LDS MFMA. ---------------
// CX and Wo-bf16 are L2-resident -> direct global fragment loads, no W staging, no
// barriers except the single LN cross-wave reduce (was 17 barriers).
__global__ __attribute__((amdgpu_waves_per_eu(4, 8))) __launch_bounds__(256) void k_outln(
    const u16* __restrict__ CX, const u16* __restrict__ Wob,
    const float* __restrict__ bo, const float* __restrict__ xs,
    const float* __restrict__ lgm, const float* __restrict__ lbt,
    float* __restrict__ Out)
{
  __shared__ float parts[4][16][2];
  const int t = threadIdx.x;
  const int wv = t>>6, ln = t&15, qd = (t&63)>>4;
  const int m0 = blockIdx.x * 16;
  const int n0w = wv*64;

  f32x4 z4 = {0.0f,0.0f,0.0f,0.0f};
  f32x4 acc[4];
  #pragma unroll
  for (int i=0;i<4;i++) acc[i] = z4;

  #pragma unroll
  for (int kt=0; kt<8; kt++){
    bf16x8 a = *(const bf16x8*)(CX + (size_t)(m0 + ln)*256 + kt*32 + qd*8);
    #pragma unroll
    for (int ni=0;ni<4;ni++){
      bf16x8 b = *(const bf16x8*)(Wob + (size_t)(n0w + ni*16 + ln)*256 + kt*32 + qd*8);
      acc[ni] = MFMA16(a, b, acc[ni]);
    }
  }

  float psum[4]={0,0,0,0}, psq[4]={0,0,0,0};
  #pragma unroll
  for (int ni=0;ni<4;ni++){
    const int col = n0w + ni*16 + ln;
    const float bias = bo[col];
    #pragma unroll
    for (int r=0;r<4;r++){
      const int row = qd*4 + r;
      float y = acc[ni][r] + bias + xs[(size_t)(m0+row)*256 + col];
      acc[ni][r] = y;
      psum[r] += y; psq[r] += y*y;
    }
  }
  #pragma unroll
  for (int r=0;r<4;r++){
    float a1 = psum[r], a2 = psq[r];
    #pragma unroll
    for (int m=1;m<16;m<<=1){ a1 += __shfl_xor(a1,m,16); a2 += __shfl_xor(a2,m,16); }
    if (ln == 0){
      parts[wv][qd*4 + r][0] = a1;
      parts[wv][qd*4 + r][1] = a2;
    }
  }
  __syncthreads();
  #pragma unroll
  for (int r=0;r<4;r++){
    const int row = qd*4 + r;
    float s1 = parts[0][row][0] + parts[1][row][0] + parts[2][row][0] + parts[3][row][0];
    float s2 = parts[0][row][1] + parts[1][row][1] + parts[2][row][1] + parts[3][row][1];
    float mu  = s1 * 0.00390625f;
    float var = s2 * 0.00390625f - mu*mu;
    float rs = rsqrtf(var + 1e-5f);
    #pragma unroll
    for (int ni=0;ni<4;ni++){
      const int col = n0w + ni*16 + ln;
      Out[(size_t)(m0+row)*256 + col] = (acc[ni][r] - mu)*rs*lgm[col] + lbt[col];
    }
  }
}

// -----------------------------------------------------------------------------------------
extern "C" void kernel_launch(void* const* d_in, const int* in_sizes, int n_in,
                              void* d_out, int out_size, void* d_ws, size_t ws_size,
                              hipStream_t stream)
{
  const float* x   = (const float*)d_in[0];
  const float* wq  = (const float*)d_in[1];
  const float* bq  = (const float*)d_in[2];
  const float* wk  = (const float*)d_in[3];
  const float* bk  = (const float*)d_in[4];
  const float* wv_ = (const float*)d_in[5];
  const float* bv  = (const float*)d_in[6];
  const float* wo  = (const float*)d_in[7];
  const float* bo  = (const float*)d_in[8];
  const float* lng = (const float*)d_in[9];
  const float* lnb = (const float*)d_in[10];
  const float* dib = (const float*)d_in[11];
  const float* drb = (const float*)d_in[12];

  // ws: ebtab 128K | CX 4MB | Vt 4MB | sden 256K | Wo-bf16 128K = 8.91 MB.
  // d_out f32: y [0,8MB) ; attn_w [8MB, 41.5MB).
  //   Q bf16 at y [0,4M), K bf16 at y [4M,8M): dead before k_outln writes y (serial).
  //   X-bf16 (4MB) + Wq/Wk/Wv-bf16 (384K) live at the START of the attn_w region:
  //   consumed by k_proj (launch 2), dead before k_attn_aw (launch 4) writes attn_w.
  char*  ws    = (char*)d_ws;
  float* ebtab = (float*)ws;
  u16*   CX    = (u16*)(ws + 131072);
  u16*   Vt    = (u16*)(ws + 131072 + 4194304);
  float* sden  = (float*)(ws + 131072 + 8388608);
  u16*   Wob   = (u16*)(ws + 131072 + 8388608 + 262144);
  float* y     = (float*)d_out;
  float* aw    = y + 2097152;
  u16*   Q     = (u16*)y;
  u16*   K     = (u16*)((char*)y + 4194304);
  u16*   Xb    = (u16*)aw;
  u16*   Wqb   = (u16*)((char*)aw + 4194304);
  u16*   Wkb   = (u16*)((char*)aw + 4194304 + 131072);
  u16*   Wvb   = (u16*)((char*)aw + 4194304 + 262144);

  const float qscale = 0.25503486f;   // log2(e)/sqrt(32) folded into Q

  k_convert<<<1044, 256, 0, stream>>>(x, Xb, wq, wk, wv_, wo, Wqb, Wkb, Wvb, Wob,
                                      dib, drb, ebtab);
  k_proj<<<dim3(512, 3), 256, 0, stream>>>(Xb, Wqb, bq, Wkb, bk, Wvb, bv,
                                           Q, K, Vt, qscale);
  k_attn_ctx<<<dim3(64, 8, 8), 256, 0, stream>>>(Q, K, Vt, ebtab, CX, sden);
  k_attn_aw<<<dim3(64, 8, 4), 256, 0, stream>>>(Q, K, sden, aw);
  k_outln<<<512, 256, 0, stream>>>(CX, Wob, bo, x, lng, lnb, y);
}

// Round 12
// 226.352 us; speedup vs baseline: 1.3173x; 1.0824x over previous
//
#include <hip/hip_runtime.h>
#include <stdint.h>

typedef uint16_t u16;
typedef uint32_t u32;
typedef __bf16 bf16_t;
typedef __bf16 bf16x8 __attribute__((ext_vector_type(8)));
typedef float  f32x4  __attribute__((ext_vector_type(4)));

#define MFMA16(a,b,c) __builtin_amdgcn_mfma_f32_16x16x32_bf16(a,b,c,0,0,0)

static __device__ __forceinline__ u16 f2bf(float f){
  union { bf16_t b; u16 u; } cv; cv.b = (bf16_t)f; return cv.u;
}
static __device__ __forceinline__ u32 pack2(float a, float b){
  return (u32)f2bf(a) | ((u32)f2bf(b) << 16);
}

// ---------------- K0: exp(bias) table [dh+31][h][dw+31] (63*512 f32) ----------------------
__global__ __launch_bounds__(256) void k_bias_setup(
    const float* __restrict__ dist_bias, const float* __restrict__ dir_bias,
    float* __restrict__ ebtab)
{
  int tid = blockIdx.x*256 + threadIdx.x;
  if (tid >= 63*63) return;
  int dhi = tid / 63, dwi = tid % 63;
  int dh = dhi - 31, dw = dwi - 31;
  int r2 = dh*dh + dw*dw;
  int dist = (int)sqrtf((float)r2);
  if (dist > 59) dist = 59;
  int dir;
  if (dh==0 && dw==0)      dir = 0;
  else if (dh==0)          dir = (dw>0) ? 8  : 0;
  else if (dw==0)          dir = (dh>0) ? 12 : 4;
  else if (dh==dw)         dir = (dh>0) ? 10 : 2;
  else if (dh==-dw)        dir = (dh>0) ? 14 : 6;
  else {
    float ang = atan2f((float)dh, (float)dw) + 3.14159265358979323846f;
    int k = (int)floorf(ang * 2.5464790894703254f);
    dir = k & 15;
  }
  for (int h=0; h<8; h++){
    ebtab[dhi*512 + h*64 + dwi] = expf(dist_bias[dist*8+h] + dir_bias[dir*8+h]);
  }
}

// ---------------- K1: fused Q/K/V projection. blockIdx.y selects matrix. ------------------
// C[8192,256] = X @ W^T + b (f32 in, bf16 MFMA, bf16 out), reg-prefetch double-buffered.
// Wsh/Cs union keeps LDS at 35.8KB -> 3 blocks/CU resident in one dispatch round.
// (r11 lesson: zero-LDS direct-fragment proj is SLOWER — fragment loads touch 16 cache
// lines/instr; LDS staging pays off when loads dominate the kernel. Keep this version.)
__global__ __attribute__((amdgpu_waves_per_eu(3, 3))) __launch_bounds__(256) void k_proj3(
    const float* __restrict__ X,
    const float* __restrict__ Wq, const float* __restrict__ Bq,
    const float* __restrict__ Wk, const float* __restrict__ Bk,
    const float* __restrict__ Wv, const float* __restrict__ Bvv,
    u16* __restrict__ Qo, u16* __restrict__ Ko, u16* __restrict__ Vo,
    float qscale)
{
  const float* W; const float* Bv; u16* Out; float scale; int vt_mode;
  if (blockIdx.y == 0)      { W = Wq; Bv = Bq;  Out = Qo; scale = qscale; vt_mode = 0; }
  else if (blockIdx.y == 1) { W = Wk; Bv = Bk;  Out = Ko; scale = 1.0f;   vt_mode = 0; }
  else                      { W = Wv; Bv = Bvv; Out = Vo; scale = 1.0f;   vt_mode = 1; }

  __shared__ bf16_t Xs[32*40];
  __shared__ __align__(16) char UU[33280];   // union: Wsh bf16[256*40]=20480B | Cs f32[32*260]=33280B
  bf16_t* Wsh = (bf16_t*)UU;
  float*  Cs  = (float*)UU;
  const int t = threadIdx.x;
  const int wv = t>>6, ln = t&15, qd = (t&63)>>4;
  const int wm = wv & 1, wn = wv >> 1;
  const int m0 = blockIdx.x * 32;

  f32x4 z4 = {0.0f,0.0f,0.0f,0.0f};
  f32x4 acc[8];
  #pragma unroll
  for (int i=0;i<8;i++) acc[i] = z4;

  f32x4 XR; f32x4 WR[8];
  XR = *(const f32x4*)(X + (size_t)(m0 + (t>>3))*256 + (t&7)*4);
  #pragma unroll
  for (int j=0;j<8;j++)
    WR[j] = *(const f32x4*)(W + (size_t)((t>>3)+32*j)*256 + (t&7)*4);

  for (int kt=0; kt<8; kt++){
    __syncthreads();
    { int m = t>>3, k0 = (t&7)*4;
      uint2 pk; pk.x = pack2(XR[0], XR[1]); pk.y = pack2(XR[2], XR[3]);
      *(uint2*)&Xs[m*40 + k0] = pk;
    }
    #pragma unroll
    for (int j=0;j<8;j++){
      int n = (t>>3) + 32*j, k0 = (t&7)*4;
      uint2 pk; pk.x = pack2(WR[j][0], WR[j][1]); pk.y = pack2(WR[j][2], WR[j][3]);
      *(uint2*)&Wsh[n*40 + k0] = pk;
    }
    __syncthreads();
    if (kt < 7){
      XR = *(const f32x4*)(X + (size_t)(m0 + (t>>3))*256 + (kt+1)*32 + (t&7)*4);
      #pragma unroll
      for (int j=0;j<8;j++)
        WR[j] = *(const f32x4*)(W + (size_t)((t>>3)+32*j)*256 + (kt+1)*32 + (t&7)*4);
    }
    bf16x8 a = *(const bf16x8*)&Xs[(wm*16+ln)*40 + qd*8];
    #pragma unroll
    for (int ni=0;ni<8;ni++){
      bf16x8 bb = *(const bf16x8*)&Wsh[(wn*128 + ni*16 + ln)*40 + qd*8];
      acc[ni] = MFMA16(a, bb, acc[ni]);
    }
  }
  __syncthreads();   // Wsh dead after this point; Cs takes over the union
  #pragma unroll
  for (int ni=0;ni<8;ni++){
    const int col = wn*128 + ni*16 + ln;
    const float bias = Bv[col];
    #pragma unroll
    for (int r=0;r<4;r++){
      Cs[(wm*16 + qd*4 + r)*260 + col] = (acc[ni][r] + bias) * scale;
    }
  }
  __syncthreads();
  if (!vt_mode){
    int row = t>>3, c0 = (t&7)*32;
    u16* op = Out + (size_t)(m0+row)*256 + c0;
    #pragma unroll
    for (int i=0;i<4;i++){
      f32x4 v0 = *(const f32x4*)&Cs[row*260 + c0 + i*8];
      f32x4 v1 = *(const f32x4*)&Cs[row*260 + c0 + i*8 + 4];
      union { u16 h[8]; uint4 v; } pk;
      #pragma unroll
      for (int e=0;e<4;e++){ pk.h[e] = f2bf(v0[e]); pk.h[4+e] = f2bf(v1[e]); }
      *(uint4*)(op + i*8) = pk.v;
    }
  } else {
    const int n = t;
    const int b = m0 >> 10, s0 = m0 & 1023;
    u16* op = Out + (size_t)(b*256 + n)*1024 + s0;
    #pragma unroll
    for (int i=0;i<4;i++){
      union { u16 h[8]; uint4 v; } pk;
      #pragma unroll
      for (int e=0;e<8;e++) pk.h[e] = f2bf(Cs[(i*8+e)*260 + n]);
      *(uint4*)(op + i*8) = pk.v;
    }
  }
}

// ---------------- K2a: attention ctx pass: one head per block, kt-range per wave. ---------
// Grid (64 qt, 8 b, 8 h) = 4096 blocks; wave wv owns kt in [wv*8, wv*8+8). Cross-wave
// combine of se/sb/oacc in LDS (2 barriers). SINGLE CHANGE vs r9 baseline (221.9us,
// ctx=69us @ 39% occupancy): waves_per_eu (4,4) -> (4,8). The max=4 term was the only
// binding occupancy cap (52 VGPR, 14.3KB LDS both allow 8 blocks/CU). min=4 keeps the
// allocator budget at 128 regs (kernel needs 52 -> no spill; r8's (8,8) disaster was a
// kernel needing ~100 regs squeezed to 32).
__global__ __attribute__((amdgpu_waves_per_eu(4, 8))) __launch_bounds__(256) void k_attn_ctx(
    const u16* __restrict__ Qg, const u16* __restrict__ Kg,
    const u16* __restrict__ Vtg, const float* __restrict__ ebtab,
    u16* __restrict__ ctx, float* __restrict__ sden)
{
  __shared__ bf16_t Ps[4][16*40];          // 5120 B, wave-private transpose buffer
  __shared__ float  red[2][4][16];         // 512 B: se/sb per wave per row
  __shared__ float  invb[16];              // 64 B
  __shared__ float  opl[4][16][33];        // 8448 B (pad 33: no 4-way bank alias)

  const int t  = threadIdx.x;
  const int wv = t >> 6;
  const int ln = t & 15;
  const int qd = (t & 63) >> 4;
  const int lane = t & 63;
  const int b  = blockIdx.y;
  const int qt = blockIdx.x;
  const int h  = blockIdx.z;
  const int kt0 = wv*8;
  const int qh_img = qt >> 1;
  const int qw0 = (qt & 1) * 16;

  const u16* Qb  = Qg  + (size_t)(b*1024 + qt*16) * 256;
  const u16* Kb  = Kg  + (size_t)b * 1024 * 256;
  const u16* Vtb = Vtg + (size_t)b * 256 * 1024;

  f32x4 z4 = {0.0f,0.0f,0.0f,0.0f};

  bf16x8 aq = *(const bf16x8*)(Qb + ln*256 + h*32 + qd*8);

  float se[4] = {0,0,0,0}, sb[4] = {0,0,0,0};
  f32x4 oacc[2]; oacc[0]=z4; oacc[1]=z4;

  for (int kti=0; kti<8; kti++){
    const int kt = kt0 + kti;
    float cE = ebtab[(size_t)(kt - qh_img + 31)*512 + h*64 + lane];

    #pragma unroll
    for (int kh=0;kh<2;kh++){
      bf16x8 bk = *(const bf16x8*)(Kb + (size_t)(kt*32 + kh*16 + ln)*256 + h*32 + qd*8);
      f32x4 sc = MFMA16(aq, bk, z4);
      #pragma unroll
      for (int r=0;r<4;r++){
        float e  = exp2f(sc[r]);                 // Q pre-scaled by log2e/sqrt(dk)
        int idx = kh*16 + ln - (qw0 + qd*4 + r) + 31;   // dw+31 in [0,62]
        float ebv = __shfl(cE, idx);
        float eb = e * ebv;
        se[r] += e;
        sb[r] += eb;
        Ps[wv][(qd*4+r)*40 + kh*16 + ln] = (bf16_t)eb;   // unnormalized
      }
    }
    // per-wave in-order LDS + alias-visible dependence orders Ps write->read
    bf16x8 ap = *(const bf16x8*)&Ps[wv][ln*40 + qd*8];
    #pragma unroll
    for (int nh=0;nh<2;nh++){
      bf16x8 bv = *(const bf16x8*)(Vtb + (size_t)(h*32 + nh*16 + ln)*1024 + kt*32 + qd*8);
      oacc[nh] = MFMA16(ap, bv, oacc[nh]);
    }
  }

  // reduce partial denominator sums across the 16 column-lanes (same qd group)
  #pragma unroll
  for (int r=0;r<4;r++){
    #pragma unroll
    for (int m=1;m<16;m<<=1){
      se[r] += __shfl_xor(se[r], m, 16);
      sb[r] += __shfl_xor(sb[r], m, 16);
    }
  }
  if (ln == 0){
    #pragma unroll
    for (int r=0;r<4;r++){
      red[0][wv][qd*4+r] = se[r];
      red[1][wv][qd*4+r] = sb[r];
    }
  }
  // stage this wave's PV partial
  #pragma unroll
  for (int nh=0;nh<2;nh++)
    #pragma unroll
    for (int r=0;r<4;r++)
      opl[wv][qd*4+r][nh*16+ln] = oacc[nh][r];
  __syncthreads();

  if (t < 16){
    float s = red[0][0][t] + red[0][1][t] + red[0][2][t] + red[0][3][t];
    float bsum = red[1][0][t] + red[1][1][t] + red[1][2][t] + red[1][3][t];
    sden[(size_t)(b*8 + h)*1024 + qt*16 + t] = 1.0f / s;
    invb[t] = 1.0f / bsum;
  }
  __syncthreads();

  { // 256 threads: 16 rows x 32 cols, 2 cols/thread -> ctx bf16
    const int row = t >> 4, c = (t & 15)*2;
    float o0 = opl[0][row][c]   + opl[1][row][c]   + opl[2][row][c]   + opl[3][row][c];
    float o1 = opl[0][row][c+1] + opl[1][row][c+1] + opl[2][row][c+1] + opl[3][row][c+1];
    float iv = invb[row];
    *(u32*)(ctx + (size_t)(b*1024 + qt*16 + row)*256 + h*32 + c) = pack2(o0*iv, o1*iv);
  }
}

// ---------------- K2b: attn_w pass. kt-parallel, grid (64,8,4) = 2048 blocks. ------------
// Q fragments for all 8 heads hoisted out of the head loop (32 VGPR) -> 32 independent
// MFMA/exp2 streams per wave; (4,4) gives the allocator the 128-reg budget for it.
__global__ __attribute__((amdgpu_waves_per_eu(4, 4))) __launch_bounds__(256) void k_attn_aw(
    const u16* __restrict__ Qg, const u16* __restrict__ Kg,
    const float* __restrict__ sden, float* __restrict__ AW)
{
  const int t  = threadIdx.x;
  const int wv = t >> 6;
  const int ln = t & 15;
  const int qd = (t & 63) >> 4;
  const int b  = blockIdx.y;
  const int qt = blockIdx.x;
  const int kt0 = blockIdx.z*8 + wv*2;

  const u16* Qb = Qg + (size_t)(b*1024 + qt*16) * 256;
  const u16* Kb = Kg + (size_t)b * 1024 * 256;

  f32x4 z4 = {0.0f,0.0f,0.0f,0.0f};

  bf16x8 aqh[8];
  #pragma unroll
  for (int h=0;h<8;h++)
    aqh[h] = *(const bf16x8*)(Qb + ln*256 + h*32 + qd*8);

  float aw0[2][2][4];
  #pragma unroll
  for (int k2=0;k2<2;k2++)
    #pragma unroll
    for (int kh=0;kh<2;kh++)
      #pragma unroll
      for (int r=0;r<4;r++) aw0[k2][kh][r] = 0.0f;

  #pragma unroll
  for (int h=0;h<8;h++){
    float iv[4];
    #pragma unroll
    for (int r=0;r<4;r++)
      iv[r] = sden[(size_t)(b*8 + h)*1024 + qt*16 + qd*4 + r];
    #pragma unroll
    for (int k2=0;k2<2;k2++){
      #pragma unroll
      for (int kh=0;kh<2;kh++){
        bf16x8 bk = *(const bf16x8*)(Kb + (size_t)((kt0+k2)*32 + kh*16 + ln)*256 + h*32 + qd*8);
        f32x4 sc = MFMA16(aqh[h], bk, z4);
        #pragma unroll
        for (int r=0;r<4;r++)
          aw0[k2][kh][r] += exp2f(sc[r]) * iv[r];
      }
    }
  }
  #pragma unroll
  for (int k2=0;k2<2;k2++)
    #pragma unroll
    for (int kh=0;kh<2;kh++)
      #pragma unroll
      for (int r=0;r<4;r++)
        AW[(size_t)(b*1024 + qt*16 + qd*4 + r)*1024 + (kt0+k2)*32 + kh*16 + ln]
            = aw0[k2][kh][r] * 0.125f;
}

// ---------------- K3: out = ctx@Wo^T + bo ; y = LN(out + x). f32 out. ---------------------
// 16-row blocks: grid 512 = 2 blocks/CU. Wave wv owns cols [wv*64, wv*64+64).
// Wsh/Ys LDS union -> 22.3KB/block.
__global__ __attribute__((amdgpu_waves_per_eu(2, 2))) __launch_bounds__(256) void k_outln(
    const u16* __restrict__ CX, const float* __restrict__ Wo,
    const float* __restrict__ bo, const float* __restrict__ xs,
    const float* __restrict__ lgm, const float* __restrict__ lbt,
    float* __restrict__ Out)
{
  __shared__ bf16_t Cts[16*40];
  __shared__ __align__(16) char UU[20480];   // union: Wsh bf16[256*40] | Ys f32[16*260]=16640B
  bf16_t* Wsh = (bf16_t*)UU;
  float*  Ys  = (float*)UU;
  __shared__ float  parts[4][16][2];
  const int t = threadIdx.x;
  const int wv = t>>6, ln = t&15, qd = (t&63)>>4;
  const int m0 = blockIdx.x * 16;

  f32x4 z4 = {0.0f,0.0f,0.0f,0.0f};
  f32x4 acc[4];
  #pragma unroll
  for (int i=0;i<4;i++) acc[i] = z4;

  u32 CR; f32x4 WR[8];
  CR = *(const u32*)(CX + (size_t)(m0 + (t>>4))*256 + (t&15)*2);
  #pragma unroll
  for (int j=0;j<8;j++)
    WR[j] = *(const f32x4*)(Wo + (size_t)((t>>3)+32*j)*256 + (t&7)*4);

  for (int kt=0; kt<8; kt++){
    __syncthreads();
    *(u32*)&Cts[(t>>4)*40 + (t&15)*2] = CR;
    #pragma unroll
    for (int j=0;j<8;j++){
      int n = (t>>3) + 32*j, k0 = (t&7)*4;
      uint2 pk; pk.x = pack2(WR[j][0], WR[j][1]); pk.y = pack2(WR[j][2], WR[j][3]);
      *(uint2*)&Wsh[n*40 + k0] = pk;
    }
    __syncthreads();
    if (kt < 7){
      CR = *(const u32*)(CX + (size_t)(m0 + (t>>4))*256 + (kt+1)*32 + (t&15)*2);
      #pragma unroll
      for (int j=0;j<8;j++)
        WR[j] = *(const f32x4*)(Wo + (size_t)((t>>3)+32*j)*256 + (kt+1)*32 + (t&7)*4);
    }
    bf16x8 a = *(const bf16x8*)&Cts[ln*40 + qd*8];
    #pragma unroll
    for (int ni=0;ni<4;ni++){
      bf16x8 bb = *(const bf16x8*)&Wsh[(wv*64 + ni*16 + ln)*40 + qd*8];
      acc[ni] = MFMA16(a, bb, acc[ni]);
    }
  }

  float psum[4]={0,0,0,0}, psq[4]={0,0,0,0};
  #pragma unroll
  for (int ni=0;ni<4;ni++){
    const int col = wv*64 + ni*16 + ln;
    const float bias = bo[col];
    #pragma unroll
    for (int r=0;r<4;r++){
      const int row = qd*4 + r;
      float y = acc[ni][r] + bias + xs[(size_t)(m0+row)*256 + col];
      acc[ni][r] = y;
      psum[r] += y; psq[r] += y*y;
    }
  }
  #pragma unroll
  for (int r=0;r<4;r++){
    float a1 = psum[r], a2 = psq[r];
    #pragma unroll
    for (int m=1;m<16;m<<=1){ a1 += __shfl_xor(a1,m,16); a2 += __shfl_xor(a2,m,16); }
    if (ln == 0){
      parts[wv][qd*4 + r][0] = a1;
      parts[wv][qd*4 + r][1] = a2;
    }
  }
  __syncthreads();   // also: all Wsh reads done -> Ys may take over the union
  #pragma unroll
  for (int r=0;r<4;r++){
    const int row = qd*4 + r;
    float s1 = parts[0][row][0] + parts[1][row][0] + parts[2][row][0] + parts[3][row][0];
    float s2 = parts[0][row][1] + parts[1][row][1] + parts[2][row][1] + parts[3][row][1];
    float mu  = s1 * 0.00390625f;
    float var = s2 * 0.00390625f - mu*mu;
    float rs = rsqrtf(var + 1e-5f);
    #pragma unroll
    for (int ni=0;ni<4;ni++){
      const int col = wv*64 + ni*16 + ln;
      Ys[row*260 + col] = (acc[ni][r] - mu)*rs*lgm[col] + lbt[col];
    }
  }
  __syncthreads();
  { int row = t>>4, c0 = (t&15)*16;
    float* op = Out + (size_t)(m0+row)*256 + c0;
    #pragma unroll
    for (int i=0;i<4;i++)
      *(f32x4*)(op + 4*i) = *(const f32x4*)&Ys[row*260 + c0 + 4*i];
  }
}

// -----------------------------------------------------------------------------------------
extern "C" void kernel_launch(void* const* d_in, const int* in_sizes, int n_in,
                              void* d_out, int out_size, void* d_ws, size_t ws_size,
                              hipStream_t stream)
{
  const float* x   = (const float*)d_in[0];
  const float* wq  = (const float*)d_in[1];
  const float* bq  = (const float*)d_in[2];
  const float* wk  = (const float*)d_in[3];
  const float* bk  = (const float*)d_in[4];
  const float* wv_ = (const float*)d_in[5];
  const float* bv  = (const float*)d_in[6];
  const float* wo  = (const float*)d_in[7];
  const float* bo  = (const float*)d_in[8];
  const float* lng = (const float*)d_in[9];
  const float* lnb = (const float*)d_in[10];
  const float* dib = (const float*)d_in[11];
  const float* drb = (const float*)d_in[12];

  // ws: ebtab 128K | CX bf16 4MB | Vt bf16 4MB | sden f32 256K = 8.63 MB.
  // d_out f32: y [0, 8MB) ; attn_w [8MB, 41.5MB).
  //   Q bf16 at y [0,4M), K bf16 at y [4M,8M) -> dead before k_outln writes y.
  char*  ws    = (char*)d_ws;
  float* ebtab = (float*)ws;
  u16*   CX    = (u16*)(ws + 131072);
  u16*   Vt    = (u16*)(ws + 131072 + 4194304);
  float* sden  = (float*)(ws + 131072 + 8388608);
  float* y     = (float*)d_out;
  float* aw    = y + 2097152;
  u16*   Q     = (u16*)y;
  u16*   K     = (u16*)((char*)y + 4194304);

  const float qscale = 0.25503486f;   // log2(e)/sqrt(32) folded into Q

  k_bias_setup<<<16, 256, 0, stream>>>(dib, drb, ebtab);
  k_proj3<<<dim3(256, 3), 256, 0, stream>>>(x, wq, bq, wk, bk, wv_, bv, Q, K, Vt, qscale);
  k_attn_ctx<<<dim3(64, 8, 8), 256, 0, stream>>>(Q, K, Vt, ebtab, CX, sden);
  k_attn_aw<<<dim3(64, 8, 4), 256, 0, stream>>>(Q, K, sden, aw);
  k_outln<<<512, 256, 0, stream>>>(CX, wo, bo, x, lng, lnb, y);
}